// Round 5
// baseline (183.315 us; speedup 1.0000x reference)
//
#include <hip/hip_runtime.h>

#define NUM_FRAME 300
#define LEN_FRAME 512
#define T_LEN     20000

typedef _Float16 half8  __attribute__((ext_vector_type(8)));
typedef _Float16 half4v __attribute__((ext_vector_type(4)));
typedef float    floatx4 __attribute__((ext_vector_type(4)));

// Per-pair LDS layout (halves). Bank design (32 banks x 4B = 8 "bank-quads"):
//  - A stored twice (identical), base offset 95 quads (odd): rows i&4 read copy1,
//    turning the stride-2-quad octet pattern into all-8-bank-quads-per-octet.
//  - B stored as 8 shift-copies B_c[p]=a[(p+c)&511], copy stride 65 quads (==1 mod 8):
//    lane j reads copy j&7 at 16B-aligned offset -> one ds_read_b128, octets cover
//    all 8 bank-quads exactly once.
#define A0_OFF      0      // ext x in [272,1024) at offset x-272 (752 halves)
#define A1_OFF      760    // 95 quads from A0 (odd mod 8)
#define B_OFF       1512   // 189 quads from pair base
#define B_STRIDE    520    // 65 quads, == 1 mod 8
#define PAIR_STRIDE 5672   // 709 quads (multiple of 8 halves)

__global__ __launch_bounds__(256, 3) void acorr_mfma(const float* __restrict__ in,
                                                     float* __restrict__ out) {
    __shared__ _Float16 lds[4 * PAIR_STRIDE];   // 45376 B -> 3 blocks/CU

    const int tid = threadIdx.x;

    // ---------------- staging: window -> f16 -> copy-structured LDS ----------------
    {
        const int fj = tid >> 7;           // frame within block
        const int m  = tid & 127;          // owns samples 4m..4m+3 (+8 context)
        const int x0 = 4 * m;
        const int G  = blockIdx.x * 2 + fj;
        const int bc = G / NUM_FRAME;
        const int fr = G - bc * NUM_FRAME;
        const int start = (fr == NUM_FRAME - 1)
            ? (T_LEN - LEN_FRAME)
            : (int)((double)fr * ((double)(T_LEN - LEN_FRAME) / (double)(NUM_FRAME - 1)));
        const float2* src = (const float2*)(in + (size_t)2 * ((size_t)bc * T_LEN + start));

        float2 v[12];
        float  wd[12];
        #pragma unroll
        for (int r = 0; r < 12; ++r) {
            int n = (x0 + r) & 511;                 // circular
            v[r]  = src[n];
            wd[r] = 0.5f - 0.5f * __cosf((float)n * (6.283185307179586f / LEN_FRAME));
        }

        #pragma unroll
        for (int c01 = 0; c01 < 2; ++c01) {
            _Float16 hh[12];
            #pragma unroll
            for (int r = 0; r < 12; ++r)
                hh[r] = (_Float16)((c01 ? v[r].y : v[r].x) * wd[r]);

            _Float16* P = &lds[(fj * 2 + c01) * PAIR_STRIDE];
            half4v q0 = {hh[0], hh[1], hh[2], hh[3]};

            // A ext image: x in [512,1024) at x-272, and x in [272,512) at x-272
            *(half4v*)&P[A0_OFF + x0 + 240] = q0;
            *(half4v*)&P[A1_OFF + x0 + 240] = q0;
            if (x0 >= 272) {
                *(half4v*)&P[A0_OFF + x0 - 272] = q0;
                *(half4v*)&P[A1_OFF + x0 - 272] = q0;
            }
            // B shift-copies (+8-half tail duplicated by threads m<2)
            #pragma unroll
            for (int c = 0; c < 8; ++c) {
                half4v qc = {hh[c], hh[c + 1], hh[c + 2], hh[c + 3]};
                *(half4v*)&P[B_OFF + B_STRIDE * c + x0] = qc;
                if (m < 2)
                    *(half4v*)&P[B_OFF + B_STRIDE * c + 512 + x0] = qc;
            }
        }
    }
    __syncthreads();

    // ---------------- MFMA main: wave w = pair w; 16 x (16x16x32 f16) ----------------
    const int w    = tid >> 6;
    const int lane = tid & 63;
    const int il   = lane & 15;    // A row i / B col j
    const int q    = lane >> 4;

    const _Float16* P  = &lds[w * PAIR_STRIDE];
    const int x0A = 512 + 8 * q - 16 * il;                       // [272,536]
    const _Float16* aP = P + ((il & 4) ? A1_OFF : A0_OFF) + (x0A - 272);
    const _Float16* bP = P + B_OFF + B_STRIDE * (il & 7) + 8 * q + 8 * (il >> 3);

    floatx4 acc = {0.f, 0.f, 0.f, 0.f};
    #pragma unroll
    for (int u = 0; u < 16; ++u) {
        half8 av = *(const half8*)(aP + 32 * u);   // 16B-aligned ds_read_b128
        half8 bv = *(const half8*)(bP + 32 * u);   // 16B-aligned ds_read_b128
        acc = __builtin_amdgcn_mfma_f32_16x16x32_f16(av, bv, acc, 0, 0, 0);
    }

    // ---------------- epilogue: relu, 1/sqrt(acf0), channel mean, store ----------------
    // C/D layout: col j = lane&15, row i = 4q + reg -> lag = 16i + j.
    float n0  = __shfl(acc[0], 0, 64);
    float n0r = fmaxf(n0, 0.f);
    float inv = (n0r == 0.f) ? 1.f : rsqrtf(n0r);
    float r0 = fmaxf(acc[0], 0.f) * inv;
    float r1 = fmaxf(acc[1], 0.f) * inv;
    float r2 = fmaxf(acc[2], 0.f) * inv;
    float r3 = fmaxf(acc[3], 0.f) * inv;

    __syncthreads();                              // main-loop LDS reads done
    float* scr = (float*)&lds[0];
    const int f   = w >> 1;
    const int idx = f * 256 + q * 64 + il;
    if (w & 1) {                                  // ch1 -> scratch
        scr[idx +  0] = r0; scr[idx + 16] = r1;
        scr[idx + 32] = r2; scr[idx + 48] = r3;
    }
    __syncthreads();
    if (!(w & 1)) {                               // ch0: mean + store
        const int G = blockIdx.x * 2 + f;
        float* ob = out + (size_t)G * 256 + q * 64 + il;
        ob[ 0] = 0.5f * (r0 + scr[idx +  0]);
        ob[16] = 0.5f * (r1 + scr[idx + 16]);
        ob[32] = 0.5f * (r2 + scr[idx + 32]);
        ob[48] = 0.5f * (r3 + scr[idx + 48]);
    }
}

extern "C" void kernel_launch(void* const* d_in, const int* in_sizes, int n_in,
                              void* d_out, int out_size, void* d_ws, size_t ws_size,
                              hipStream_t stream) {
    const float* in = (const float*)d_in[0];
    float* out = (float*)d_out;
    dim3 grid(30000);    // 60000 frames / 2 per block
    dim3 block(256);
    acorr_mfma<<<grid, block, 0, stream>>>(in, out);
}

// Round 6
// 135.472 us; speedup vs baseline: 1.3532x; 1.3532x over previous
//
#include <hip/hip_runtime.h>

#define NUM_FRAME 300
#define LEN_FRAME 512
#define T_LEN     20000

typedef _Float16 half8  __attribute__((ext_vector_type(8)));
typedef _Float16 half4v __attribute__((ext_vector_type(4)));
typedef float    floatx4 __attribute__((ext_vector_type(4)));
typedef unsigned int uint32;

// Per-pair LDS layout (halves):
//  A image: ext a[x], x in [272,1024) stored UNPADDED at x-272. b128 reads hit
//    bank-quads (q-2i) mod 8 -> exactly 8 lanes per bank-quad = b128 floor.
//  BEv: a[p], p in [0,544);  BOd: a[p+1] (shift-1 copy for odd cols).
//    BO_OFF - BE_OFF = 544 halves = 272 dwords == 16 (mod 32): the odd-image
//    bank window is the 16-bank complement of the even image -> uniform
//    2/bank per b32 (4/bank for any read2 pairing) = conflict-free.
#define A_OFF   0
#define BE_OFF  752
#define BO_OFF  1296
#define PAIR    1840          // 3680 B per (frame,ch)
#define SCR_OFF (4 * PAIR)    // 1024 halves = 512 floats epilogue scratch

__global__ __launch_bounds__(256, 8) void acorr_mfma(const float* __restrict__ in,
                                                     float* __restrict__ out) {
    __shared__ _Float16 lds[4 * PAIR + 1024];   // 16768 B -> 8 blocks/CU

    const int tid = threadIdx.x;

    // ---------------- staging: window -> f16 -> A image + B parity images ----------------
    {
        const int fj = tid >> 7;           // frame within block
        const int m  = tid & 127;          // owns samples 4m..4m+3
        const int x0 = 4 * m;
        const int G  = blockIdx.x * 2 + fj;
        const int bc = G / NUM_FRAME;
        const int fr = G - bc * NUM_FRAME;
        const int start = (fr == NUM_FRAME - 1)
            ? (T_LEN - LEN_FRAME)
            : (int)((double)fr * ((double)(T_LEN - LEN_FRAME) / (double)(NUM_FRAME - 1)));
        const float2* src = (const float2*)(in + (size_t)2 * ((size_t)bc * T_LEN + start));

        float2 v0 = src[x0 + 0], v1 = src[x0 + 1], v2 = src[x0 + 2], v3 = src[x0 + 3];
        const int n5 = (x0 + 4) & 511;     // circular 5th sample for the shift-1 copy
        float2 v4 = src[n5];

        const float k2 = 6.283185307179586f / LEN_FRAME;
        float w0 = 0.5f - 0.5f * __cosf((float)(x0 + 0) * k2);
        float w1 = 0.5f - 0.5f * __cosf((float)(x0 + 1) * k2);
        float w2 = 0.5f - 0.5f * __cosf((float)(x0 + 2) * k2);
        float w3 = 0.5f - 0.5f * __cosf((float)(x0 + 3) * k2);
        float w4 = 0.5f - 0.5f * __cosf((float)n5 * k2);

        #pragma unroll
        for (int c = 0; c < 2; ++c) {
            _Float16 h0 = (_Float16)((c ? v0.y : v0.x) * w0);
            _Float16 h1 = (_Float16)((c ? v1.y : v1.x) * w1);
            _Float16 h2 = (_Float16)((c ? v2.y : v2.x) * w2);
            _Float16 h3 = (_Float16)((c ? v3.y : v3.x) * w3);
            _Float16 h4 = (_Float16)((c ? v4.y : v4.x) * w4);
            _Float16* P = &lds[(fj * 2 + c) * PAIR];
            half4v qa = {h0, h1, h2, h3};
            half4v qb = {h1, h2, h3, h4};

            *(half4v*)&P[A_OFF + x0 + 240] = qa;          // ext [512,1024)
            if (x0 >= 272)
                *(half4v*)&P[A_OFF + x0 - 272] = qa;      // ext [272,512)
            *(half4v*)&P[BE_OFF + x0] = qa;
            *(half4v*)&P[BO_OFF + x0] = qb;
            if (x0 < 16) {                                // circular tails
                *(half4v*)&P[BE_OFF + x0 + 512] = qa;
                *(half4v*)&P[BO_OFF + x0 + 512] = qb;
            }
        }
    }
    __syncthreads();

    // ---------------- MFMA main: wave w = pair w; 16 x (16x16x32 f16), K=512 ----------------
    const int w    = tid >> 6;
    const int lane = tid & 63;
    const int il   = lane & 15;    // A row i / B col j
    const int q    = lane >> 4;

    const _Float16* P  = &lds[w * PAIR];
    const _Float16* aP = P + (240 + 8 * q - 16 * il);     // ext 512+8q-16i, idx-272
    const char* bP = (il & 1)
        ? (const char*)(P + BO_OFF + 8 * q + il - 1)      // shift-1 image, dword-aligned
        : (const char*)(P + BE_OFF + 8 * q + il);

    floatx4 acc = {0.f, 0.f, 0.f, 0.f};
    #pragma unroll
    for (int u = 0; u < 16; ++u) {
        half8 av = *(const half8*)(aP + 32 * u);          // 16B-aligned ds_read_b128
        uint4 bw;
        bw.x = *(const uint32*)(bP + 64 * u + 0);
        bw.y = *(const uint32*)(bP + 64 * u + 4);
        bw.z = *(const uint32*)(bP + 64 * u + 8);
        bw.w = *(const uint32*)(bP + 64 * u + 12);
        acc = __builtin_amdgcn_mfma_f32_16x16x32_f16(av, __builtin_bit_cast(half8, bw), acc, 0, 0, 0);
    }

    // ---------------- epilogue: relu, 1/sqrt(acf0), channel mean, store ----------------
    // C/D layout: col j = lane&15, row i = 4q + reg -> lag = 16i + j.
    float n0  = __shfl(acc[0], 0, 64);
    float n0r = fmaxf(n0, 0.f);
    float inv = (n0r == 0.f) ? 1.f : rsqrtf(n0r);
    float r0 = fmaxf(acc[0], 0.f) * inv;
    float r1 = fmaxf(acc[1], 0.f) * inv;
    float r2 = fmaxf(acc[2], 0.f) * inv;
    float r3 = fmaxf(acc[3], 0.f) * inv;

    float* scr = (float*)&lds[SCR_OFF];                   // dedicated region: one barrier
    const int f   = w >> 1;
    const int idx = f * 256 + q * 64 + il;
    if (w & 1) {                                          // ch1 -> scratch
        scr[idx +  0] = r0; scr[idx + 16] = r1;
        scr[idx + 32] = r2; scr[idx + 48] = r3;
    }
    __syncthreads();
    if (!(w & 1)) {                                       // ch0: mean + store
        const int G = blockIdx.x * 2 + f;
        float* ob = out + (size_t)G * 256 + q * 64 + il;
        ob[ 0] = 0.5f * (r0 + scr[idx +  0]);
        ob[16] = 0.5f * (r1 + scr[idx + 16]);
        ob[32] = 0.5f * (r2 + scr[idx + 32]);
        ob[48] = 0.5f * (r3 + scr[idx + 48]);
    }
}

extern "C" void kernel_launch(void* const* d_in, const int* in_sizes, int n_in,
                              void* d_out, int out_size, void* d_ws, size_t ws_size,
                              hipStream_t stream) {
    const float* in = (const float*)d_in[0];
    float* out = (float*)d_out;
    dim3 grid(30000);    // 60000 frames / 2 per block
    dim3 block(256);
    acorr_mfma<<<grid, block, 0, stream>>>(in, out);
}

// Round 7
// 132.944 us; speedup vs baseline: 1.3789x; 1.0190x over previous
//
#include <hip/hip_runtime.h>

#define NUM_FRAME 300
#define LEN_FRAME 512
#define T_LEN     20000

typedef float floatx4 __attribute__((ext_vector_type(4)));
typedef unsigned int uint32;
typedef long long i64;

// Per-pair LDS layout (BYTES), fp8 e4m3 samples (scaled x32):
//  A image  [0,752):        ext a8[x], x in [272,1024) at byte x-272 (unpadded).
//    b64 reads: bank = (60+2q-4i) mod 32 -> 2 addresses/bank (i vs i+8; the two
//    q-solutions are same-address broadcast) = 2-way = free [m136].
//  B images [752, 752+4*544): 4 shift-copies b_s[p]=a8[(p+s)&511], s=0..3, read
//    as read2_b32. Stride 544 B = 136 dwords == 8 (mod 32): residue count is
//    uniform 2/bank (enumerated) = free.
#define A_OFF   0
#define B_OFF   752
#define B_STR   544
#define PAIR8   2944          // per (frame,ch), bytes
#define SCR_OFF (4 * PAIR8)   // 2048 B float scratch for channel-mean

__global__ __launch_bounds__(256, 8) void acorr_fp8(const float* __restrict__ in,
                                                    float* __restrict__ out) {
    __shared__ __align__(16) char lds8[4 * PAIR8 + 2048];   // 13824 B -> 8 blocks/CU

    const int tid = threadIdx.x;

    // ---------------- staging: window -> fp8(x32) -> A image + 4 B shift-images ----------------
    {
        const int fj = tid >> 7;           // frame within block
        const int m  = tid & 127;          // owns samples x0..x0+3 (uses 8 of context)
        const int x0 = 4 * m;
        const int G  = blockIdx.x * 2 + fj;
        const int bc = G / NUM_FRAME;
        const int fr = G - bc * NUM_FRAME;
        const int start = (fr == NUM_FRAME - 1)
            ? (T_LEN - LEN_FRAME)
            : (int)((double)fr * ((double)(T_LEN - LEN_FRAME) / (double)(NUM_FRAME - 1)));
        const float2* src = (const float2*)(in + (size_t)2 * ((size_t)bc * T_LEN + start));

        float2 v[8];
        float  wd[8];
        #pragma unroll
        for (int r = 0; r < 8; ++r) {
            int n = (x0 + r) & 511;                       // circular
            v[r]  = src[n];
            // window * 32 (fp8 scale; normalizer folds in 1/1024)
            wd[r] = (0.5f - 0.5f * __cosf((float)n * (6.283185307179586f / LEN_FRAME))) * 32.0f;
        }

        #pragma unroll
        for (int c = 0; c < 2; ++c) {
            float f[8];
            #pragma unroll
            for (int r = 0; r < 8; ++r) f[r] = (c ? v[r].y : v[r].x) * wd[r];

            int d0 = __builtin_amdgcn_cvt_pk_fp8_f32(f[0], f[1], 0,  false);
            d0     = __builtin_amdgcn_cvt_pk_fp8_f32(f[2], f[3], d0, true);
            int d1 = __builtin_amdgcn_cvt_pk_fp8_f32(f[4], f[5], 0,  false);
            d1     = __builtin_amdgcn_cvt_pk_fp8_f32(f[6], f[7], d1, true);

            char* P = &lds8[(fj * 2 + c) * PAIR8];
            *(int*)(P + A_OFF + x0 + 240) = d0;           // ext [512,1024)
            if (x0 >= 272)
                *(int*)(P + A_OFF + x0 - 272) = d0;       // ext [272,512)

            #pragma unroll
            for (int s = 0; s < 4; ++s) {
                int ds = (s == 0) ? d0
                       : (int)__builtin_amdgcn_alignbyte((uint32)d1, (uint32)d0, (uint32)s);
                *(int*)(P + B_OFF + B_STR * s + x0) = ds;
                if (x0 < 16)                               // periodic tail (b_s has period 512)
                    *(int*)(P + B_OFF + B_STR * s + x0 + 512) = ds;
            }
        }
    }
    __syncthreads();

    // ---------------- MFMA main: wave w = pair w; 16 x (16x16x32 fp8_fp8), K=512 ----------------
    const int w    = tid >> 6;
    const int lane = tid & 63;
    const int il   = lane & 15;    // A row i / B col j
    const int q    = lane >> 4;

    const char* P  = &lds8[w * PAIR8];
    const char* aP = P + A_OFF + (240 + 8 * q - 16 * il);            // 8B-aligned
    const char* bP = P + B_OFF + B_STR * (il & 3) + 8 * q + 4 * (il >> 2);  // 4B-aligned

    floatx4 acc = {0.f, 0.f, 0.f, 0.f};
    #pragma unroll
    for (int u = 0; u < 16; ++u) {
        i64 av = *(const i64*)(aP + 32 * u);                         // ds_read_b64
        uint32 b0 = *(const uint32*)(bP + 32 * u + 0);               // ds_read2_b32
        uint32 b1 = *(const uint32*)(bP + 32 * u + 4);
        i64 bv = ((i64)(unsigned long long)b1 << 32) | (i64)b0;
        acc = __builtin_amdgcn_mfma_f32_16x16x32_fp8_fp8(av, bv, acc, 0, 0, 0);
    }

    // ---------------- epilogue: relu, 1/sqrt(acf0), channel mean, store ----------------
    // C/D layout: col j = lane&15, row i = 4q + reg -> lag = 16i + j.
    // acc = 1024 * acf (samples scaled x32): inv = rsqrt(1024*acf0)/32 = (1/1024)/sqrt(acf0).
    float n0  = __shfl(acc[0], 0, 64);
    float n0r = fmaxf(n0, 0.f);
    float inv = (n0r == 0.f) ? (1.0f / 1024.0f) : (rsqrtf(n0r) * (1.0f / 32.0f));
    float r0 = fmaxf(acc[0], 0.f) * inv;
    float r1 = fmaxf(acc[1], 0.f) * inv;
    float r2 = fmaxf(acc[2], 0.f) * inv;
    float r3 = fmaxf(acc[3], 0.f) * inv;

    float* scr = (float*)&lds8[SCR_OFF];
    const int f   = w >> 1;
    const int idx = f * 256 + q * 64 + il;
    if (w & 1) {                                          // ch1 -> scratch
        scr[idx +  0] = r0; scr[idx + 16] = r1;
        scr[idx + 32] = r2; scr[idx + 48] = r3;
    }
    __syncthreads();
    if (!(w & 1)) {                                       // ch0: mean + store
        const int G = blockIdx.x * 2 + f;
        float* ob = out + (size_t)G * 256 + q * 64 + il;
        ob[ 0] = 0.5f * (r0 + scr[idx +  0]);
        ob[16] = 0.5f * (r1 + scr[idx + 16]);
        ob[32] = 0.5f * (r2 + scr[idx + 32]);
        ob[48] = 0.5f * (r3 + scr[idx + 48]);
    }
}

extern "C" void kernel_launch(void* const* d_in, const int* in_sizes, int n_in,
                              void* d_out, int out_size, void* d_ws, size_t ws_size,
                              hipStream_t stream) {
    const float* in = (const float*)d_in[0];
    float* out = (float*)d_out;
    dim3 grid(30000);    // 60000 frames / 2 per block
    dim3 block(256);
    acorr_fp8<<<grid, block, 0, stream>>>(in, out);
}

// Round 8
// 124.722 us; speedup vs baseline: 1.4698x; 1.0659x over previous
//
#include <hip/hip_runtime.h>

#define NUM_FRAME 300
#define LEN_FRAME 512
#define T_LEN     20000

typedef float floatx4 __attribute__((ext_vector_type(4)));
typedef int   int2a   __attribute__((ext_vector_type(2), aligned(4)));
typedef unsigned int uint32;
typedef long long i64;

// Per-pair LDS layout (BYTES), fp8 e4m3 samples (scaled x32):
//  A0 [0,752):       ext a8[x], x in [272,1024) at byte x-272.
//  A1 [756,1508):    identical copy at +756 (== 4 mod 8): rows il>=8 read it, so
//    their read2_b32 dwords are ODD -> 64 lanes cover all 32 banks, <=2 distinct
//    addresses/bank per read2 half = conflict-free (vs b64's even-only 4-addr 1.58x).
//  B [1512,...): 4 shift-copies b_s[p]=a8[(p+s)&511], s=0..3, stride 544 B;
//    read as read2_b32, uniform <=2 addr/bank (enumerated, R6-verified scheme).
#define A1_OFF  756
#define B_OFF   1512
#define B_STR   544
#define PAIR8   3696          // per (frame,ch), bytes (16-aligned)
#define SCR_OFF (4 * PAIR8)   // staggered float scratch for channel-mean

__global__ __launch_bounds__(256, 8) void acorr_fp8(const float* __restrict__ in,
                                                    float* __restrict__ out) {
    __shared__ __align__(16) char lds8[4 * PAIR8 + 2112];   // 16896 B -> 8 blocks/CU

    const int tid = threadIdx.x;

    // ---------------- staging: window -> fp8(x32) -> A0/A1 + 4 B shift-images ----------------
    {
        const int fj = tid >> 7;           // frame within block
        const int m  = tid & 127;          // owns samples x0..x0+3 (+3 context)
        const int x0 = 4 * m;
        const int G  = blockIdx.x * 2 + fj;
        const int bc = G / NUM_FRAME;
        const int fr = G - bc * NUM_FRAME;
        const int start = (fr == NUM_FRAME - 1)
            ? (T_LEN - LEN_FRAME)
            : (int)((double)fr * ((double)(T_LEN - LEN_FRAME) / (double)(NUM_FRAME - 1)));
        const float2* src = (const float2*)(in + (size_t)2 * ((size_t)bc * T_LEN + start));

        float2 v[7];
        float  wd[7];
        #pragma unroll
        for (int r = 0; r < 7; ++r) {
            int n = (x0 + r) & 511;                       // circular
            v[r]  = src[n];
            // window * 32 (fp8 scale; normalizer folds in 1/1024)
            wd[r] = (0.5f - 0.5f * __cosf((float)n * (6.283185307179586f / LEN_FRAME))) * 32.0f;
        }

        #pragma unroll
        for (int c = 0; c < 2; ++c) {
            float f[7];
            #pragma unroll
            for (int r = 0; r < 7; ++r) f[r] = (c ? v[r].y : v[r].x) * wd[r];

            int d0 = __builtin_amdgcn_cvt_pk_fp8_f32(f[0], f[1], 0,  false);
            d0     = __builtin_amdgcn_cvt_pk_fp8_f32(f[2], f[3], d0, true);
            int d1 = __builtin_amdgcn_cvt_pk_fp8_f32(f[4], f[5], 0,  false);
            d1     = __builtin_amdgcn_cvt_pk_fp8_f32(f[6], 0.0f, d1, true);

            char* P = &lds8[(fj * 2 + c) * PAIR8];
            *(int*)(P + x0 + 240)          = d0;          // A0, ext [512,1024)
            *(int*)(P + A1_OFF + x0 + 240) = d0;          // A1 copy
            if (x0 >= 272) {
                *(int*)(P + x0 - 272)          = d0;      // A0, ext [272,512)
                *(int*)(P + A1_OFF + x0 - 272) = d0;
            }
            #pragma unroll
            for (int s = 0; s < 4; ++s) {
                int ds = (s == 0) ? d0
                       : (int)__builtin_amdgcn_alignbyte((uint32)d1, (uint32)d0, (uint32)s);
                *(int*)(P + B_OFF + B_STR * s + x0) = ds;
                if (x0 < 16)                               // periodic tail
                    *(int*)(P + B_OFF + B_STR * s + x0 + 512) = ds;
            }
        }
    }
    __syncthreads();

    // ---------------- MFMA main: wave w = pair w; 16 x (16x16x32 fp8_fp8), K=512 ----------------
    const int w    = tid >> 6;
    const int lane = tid & 63;
    const int il   = lane & 15;    // A row i / B col j
    const int q    = lane >> 4;

    const char* P  = &lds8[w * PAIR8];
    const char* aP = P + (240 + 8 * q - 16 * il) + ((il & 8) ? A1_OFF : 0);
    const char* bP = P + B_OFF + B_STR * (il & 3) + 8 * q + 4 * (il >> 2);

    floatx4 acc = {0.f, 0.f, 0.f, 0.f};
    #pragma unroll
    for (int u = 0; u < 16; ++u) {
        int2a av = *(const int2a*)(aP + 32 * u);          // ds_read2_b32, parity-staggered
        int2a bv = *(const int2a*)(bP + 32 * u);          // ds_read2_b32
        acc = __builtin_amdgcn_mfma_f32_16x16x32_fp8_fp8(
            __builtin_bit_cast(i64, av), __builtin_bit_cast(i64, bv), acc, 0, 0, 0);
    }

    // ---------------- epilogue: relu, 1/sqrt(acf0), channel mean, store ----------------
    // C/D layout: col j = lane&15, row i = 4q + reg -> lag = 16i + j.
    // acc = 1024 * acf (samples scaled x32).
    float n0  = __shfl(acc[0], 0, 64);
    float n0r = fmaxf(n0, 0.f);
    float inv = (n0r == 0.f) ? (1.0f / 1024.0f) : (rsqrtf(n0r) * (1.0f / 32.0f));
    float r0 = fmaxf(acc[0], 0.f) * inv;
    float r1 = fmaxf(acc[1], 0.f) * inv;
    float r2 = fmaxf(acc[2], 0.f) * inv;
    float r3 = fmaxf(acc[3], 0.f) * inv;

    // staggered scratch: stride 65 per q, 264 per frame -> <=2 lanes/bank per store
    float* scr = (float*)&lds8[SCR_OFF];
    const int f   = w >> 1;
    const int idx = f * 264 + q * 65 + il;
    if (w & 1) {                                          // ch1 -> scratch
        scr[idx +  0] = r0; scr[idx + 16] = r1;
        scr[idx + 32] = r2; scr[idx + 48] = r3;
    }
    __syncthreads();
    if (!(w & 1)) {                                       // ch0: mean + store
        const int G = blockIdx.x * 2 + f;
        float* ob = out + (size_t)G * 256 + q * 64 + il;
        ob[ 0] = 0.5f * (r0 + scr[idx +  0]);
        ob[16] = 0.5f * (r1 + scr[idx + 16]);
        ob[32] = 0.5f * (r2 + scr[idx + 32]);
        ob[48] = 0.5f * (r3 + scr[idx + 48]);
    }
}

extern "C" void kernel_launch(void* const* d_in, const int* in_sizes, int n_in,
                              void* d_out, int out_size, void* d_ws, size_t ws_size,
                              hipStream_t stream) {
    const float* in = (const float*)d_in[0];
    float* out = (float*)d_out;
    dim3 grid(30000);    // 60000 frames / 2 per block
    dim3 block(256);
    acorr_fp8<<<grid, block, 0, stream>>>(in, out);
}